// Round 13
// baseline (265.168 us; speedup 1.0000x reference)
//
#include <hip/hip_runtime.h>
#include <hip/hip_bf16.h>

#define BATCH 8
#define SEQ   2048
#define DIM   512
#define QB    64
#define KB    64
#define NT    512          // 8 waves
#define NKV   (SEQ / KB)   // 32 KV tiles

typedef __attribute__((ext_vector_type(8))) short short8;
typedef __attribute__((ext_vector_type(4))) float f32x4;
typedef __attribute__((ext_vector_type(4))) unsigned short ushort4v;

__device__ __forceinline__ unsigned short f2bf(float f) {
    union { float f; unsigned u; } v; v.f = f;
    return (unsigned short)((v.u + 0x7FFFu + ((v.u >> 16) & 1u)) >> 16);
}

// K-tile row swizzle (validated R4-R12).
__device__ __forceinline__ int swz(int kv) {
    return (8 * (kv & 7)) ^ (16 * ((kv >> 3) & 3)) ^ (64 * ((kv >> 3) & 1));
}

// ---- pre-pass: X fp32 -> Xbf (row-major bf16) + Xt (transposed bf16 [b][d][s])
__global__ __launch_bounds__(256)
void prep_kernel(const float* __restrict__ X,
                 unsigned short* __restrict__ Xbf,
                 unsigned short* __restrict__ Xt) {
    __shared__ unsigned short T[64][72];
    const int b  = blockIdx.z;
    const int s0 = blockIdx.x * 64;
    const int d0 = blockIdx.y * 64;
    const int tid = threadIdx.x;
    const float* Xb = X + ((size_t)b * SEQ + s0) * DIM + d0;
    unsigned short* Yb = Xbf + ((size_t)b * SEQ + s0) * DIM + d0;
    #pragma unroll
    for (int r = 0; r < 4; ++r) {
        const int s = (tid >> 4) + r * 16;
        const int d = (tid & 15) * 4;
        float4 v = *(const float4*)(Xb + (size_t)s * DIM + d);
        ushort4v h;
        h[0] = f2bf(v.x); h[1] = f2bf(v.y); h[2] = f2bf(v.z); h[3] = f2bf(v.w);
        *(ushort4v*)(Yb + (size_t)s * DIM + d) = h;
        *(ushort4v*)&T[s][d] = h;
    }
    __syncthreads();
    {
        const int d = tid >> 2;
        const int sc = (tid & 3) * 16;
        unsigned short buf[16];
        #pragma unroll
        for (int j = 0; j < 16; ++j) buf[j] = T[sc + j][d];
        unsigned short* o = Xt + ((size_t)b * DIM + d0 + d) * SEQ + s0 + sc;
        *(short8*)(o)     = *(short8*)&buf[0];
        *(short8*)(o + 8) = *(short8*)&buf[8];
    }
}

// Async DMA stage of K tile t (linear dest, pre-swizzled src). 8 instr/thread.
__device__ __forceinline__ void stage_K(const unsigned short* __restrict__ Xb,
                                        unsigned short* klds, int t, int w, int lane) {
    const unsigned short* kp = Xb + (size_t)(t * KB) * DIM;
    #pragma unroll
    for (int k = 0; k < 8; ++k) {
        const int kv = k * 8 + w;
        const int dsrc = (lane * 8) ^ swz(kv);
        const unsigned short* g = kp + (size_t)kv * DIM + dsrc;
        unsigned short* l = klds + kv * DIM;
        __builtin_amdgcn_global_load_lds(
            (__attribute__((address_space(1))) void*)(g),
            (__attribute__((address_space(3))) void*)(l), 16, 0, 0);
    }
}

// Async DMA stage of V^T tile t into vtlds[d][kv] (kv ^= 8*(d&7)). 8 instr/thread.
__device__ __forceinline__ void stage_V(const unsigned short* __restrict__ Xtb,
                                        unsigned short* vtlds, int t, int w, int lane) {
    #pragma unroll
    for (int k = 0; k < 8; ++k) {
        const int r = w * 64 + k * 8 + (lane >> 3);
        const int kvsrc = ((lane & 7) * 8) ^ (8 * (r & 7));
        const unsigned short* g = Xtb + (size_t)r * SEQ + t * KB + kvsrc;
        unsigned short* l = vtlds + (w * 64 + k * 8) * KB;
        __builtin_amdgcn_global_load_lds(
            (__attribute__((address_space(1))) void*)(g),
            (__attribute__((address_space(3))) void*)(l), 16, 0, 0);
    }
}

// score = X·X^T (no scaling), softmax, out = P·X — flash-style, bf16 MFMA.
// R13: QB=64 Q-doubling (qfrag[2] in regs -> each K-fragment read feeds 2 MFMAs,
// each V^T read feeds 4) on the R11 single-buffer counted-vmcnt DMA schedule.
// Breaks the 1-MFMA-per-ds_read_b128 cap (~680 FLOP/cy/CU) that pinned
// R7-R12 at 180-200us / 14% MfmaUtil.
__global__ __launch_bounds__(NT, 2)
void attn_fwd(const unsigned short* __restrict__ Xbf,
              const unsigned short* __restrict__ Xt,
              float* __restrict__ O) {
    const int b   = blockIdx.x & 7;          // batch -> XCD pinning
    const int qt  = blockIdx.x >> 3;         // 0..31
    const int tid = threadIdx.x;
    const int lane = tid & 63;
    const int w    = tid >> 6;
    const int col  = lane & 15;
    const int kgrp = lane >> 4;

    __shared__ alignas(16) unsigned short Klds[KB * DIM];       // 64 KB, swizzled
    __shared__ alignas(16) unsigned short Vtlds[DIM * KB];      // 64 KB, [d][kv]
    __shared__ alignas(16) float Sbuf[QB][KB + 4];              // 17.4 KB
    __shared__ alignas(16) unsigned short Pfrag[4][2][64][8];   // 8 KB, A-frag layout
    __shared__ float m_s[QB], l_s[QB], fac_s[QB];

    const unsigned short* Xb  = Xbf + (size_t)b * SEQ * DIM;
    const unsigned short* Xtb = Xt  + (size_t)b * DIM * SEQ;

    // ---- Q preload: wave w owns 32 q-rows (half qh = w>>2), kc strip = w&3
    const int qh = w >> 2;       // 0..1
    const int kc = w & 3;        // 0..3
    short8 qfrag[2][16];         // 128 VGPR (bf16 direct loads — no conversion temps)
    #pragma unroll
    for (int qq = 0; qq < 2; ++qq) {
        const int qrow = qt * QB + qh * 32 + qq * 16 + col;
        const unsigned short* qp = Xb + (size_t)qrow * DIM;
        #pragma unroll
        for (int ks = 0; ks < 16; ++ks)
            qfrag[qq][ks] = *(const short8*)(qp + ks * 32 + kgrp * 8);
    }

    if (tid < QB) { m_s[tid] = -INFINITY; l_s[tid] = 0.f; }

    f32x4 oacc[4][4];   // O[64 q][w*64 .. +64 d] : [q2][dt]  (64 VGPR)
    #pragma unroll
    for (int i = 0; i < 4; ++i)
        #pragma unroll
        for (int j = 0; j < 4; ++j)
            oacc[i][j] = (f32x4){0.f, 0.f, 0.f, 0.f};

    // ---- prologue: stage tile 0 (both), full drain once
    stage_K(Xb,  Klds,  0, w, lane);
    stage_V(Xtb, Vtlds, 0, w, lane);
    asm volatile("s_waitcnt vmcnt(0)" ::: "memory");
    __syncthreads();

    for (int t = 0; t < NKV; ++t) {
        // ---- QK^T: wave computes S[qh*32 .. +32][kc*16 .. +16]; 1 read -> 2 MFMA
        {
            const int kvrow = kc * 16 + col;
            const unsigned short* kbase = &Klds[kvrow * DIM];
            const int sw = swz(kvrow);
            f32x4 sacc0 = (f32x4){0.f,0.f,0.f,0.f};
            f32x4 sacc1 = (f32x4){0.f,0.f,0.f,0.f};
            #pragma unroll
            for (int ks = 0; ks < 16; ++ks) {
                short8 kfr = *(const short8*)(kbase + ((ks * 32 + kgrp * 8) ^ sw));
                sacc0 = __builtin_amdgcn_mfma_f32_16x16x32_bf16(qfrag[0][ks], kfr, sacc0, 0, 0, 0);
                sacc1 = __builtin_amdgcn_mfma_f32_16x16x32_bf16(qfrag[1][ks], kfr, sacc1, 0, 0, 0);
            }
            #pragma unroll
            for (int r = 0; r < 4; ++r) {
                Sbuf[qh * 32 + 0  + kgrp * 4 + r][kc * 16 + col] = sacc0[r];
                Sbuf[qh * 32 + 16 + kgrp * 4 + r][kc * 16 + col] = sacc1[r];
            }
        }
        __syncthreads();   // (B) Sbuf ready + Klds dead

        // issue next K tile into the (dead) K buffer; flies under softmax+PV
        if (t + 1 < NKV) stage_K(Xb, Klds, t + 1, w, lane);

        // ---- online softmax: 8 threads/row, 8 scores each (R4-validated mapping)
        {
            const int r = tid >> 3;     // 0..63
            const int c = tid & 7;      // 0..7
            float4 sa = *(const float4*)&Sbuf[r][c * 8];
            float4 sb = *(const float4*)&Sbuf[r][c * 8 + 4];
            float mloc = fmaxf(fmaxf(fmaxf(sa.x, sa.y), fmaxf(sa.z, sa.w)),
                               fmaxf(fmaxf(sb.x, sb.y), fmaxf(sb.z, sb.w)));
            mloc = fmaxf(mloc, __shfl_xor(mloc, 1));
            mloc = fmaxf(mloc, __shfl_xor(mloc, 2));
            mloc = fmaxf(mloc, __shfl_xor(mloc, 4));
            const float mold = m_s[r];
            const float mnew = fmaxf(mold, mloc);
            const float fac  = __expf(mold - mnew);   // exp(-inf)=0 on first tile
            float p0 = __expf(sa.x - mnew), p1 = __expf(sa.y - mnew);
            float p2 = __expf(sa.z - mnew), p3 = __expf(sa.w - mnew);
            float p4 = __expf(sb.x - mnew), p5 = __expf(sb.y - mnew);
            float p6 = __expf(sb.z - mnew), p7 = __expf(sb.w - mnew);
            float lsum = ((p0 + p1) + (p2 + p3)) + ((p4 + p5) + (p6 + p7));
            lsum += __shfl_xor(lsum, 1);
            lsum += __shfl_xor(lsum, 2);
            lsum += __shfl_xor(lsum, 4);
            short8 p8;
            p8[0] = f2bf(p0); p8[1] = f2bf(p1); p8[2] = f2bf(p2); p8[3] = f2bf(p3);
            p8[4] = f2bf(p4); p8[5] = f2bf(p5); p8[6] = f2bf(p6); p8[7] = f2bf(p7);
            // value (q=r, kv=8c+j) -> Pfrag[r>>4][c>>2][(r&15)+16*(c&3)][j]
            *(short8*)&Pfrag[r >> 4][c >> 2][(r & 15) + 16 * (c & 3)][0] = p8;
            if (c == 0) {
                m_s[r] = mnew;
                fac_s[r] = fac;
                l_s[r] = l_s[r] * fac + lsum;
            }
        }
        // drain own V(t) DMAs (8 oldest); K(t+1)'s 8 stay in flight
        if (t + 1 < NKV) { asm volatile("s_waitcnt vmcnt(8)" ::: "memory"); }
        else             { asm volatile("s_waitcnt vmcnt(0)" ::: "memory"); }
        __syncthreads();   // (C) Pfrag/fac ready + V(t) published

        // ---- rescale O, then PV: each bfr (V^T b128) feeds 4 MFMAs (q2=0..3)
        #pragma unroll
        for (int q2 = 0; q2 < 4; ++q2) {
            #pragma unroll
            for (int r = 0; r < 4; ++r) {
                const float f = fac_s[q2 * 16 + kgrp * 4 + r];
                #pragma unroll
                for (int dt = 0; dt < 4; ++dt) oacc[q2][dt][r] *= f;
            }
        }
        #pragma unroll
        for (int kc2 = 0; kc2 < 2; ++kc2) {
            const int kvb = kc2 * 32 + kgrp * 8;
            short8 afr[4];
            #pragma unroll
            for (int q2 = 0; q2 < 4; ++q2)
                afr[q2] = *(const short8*)&Pfrag[q2][kc2][lane][0];
            #pragma unroll
            for (int dt = 0; dt < 4; ++dt) {
                const int d = w * 64 + dt * 16 + col;
                const short8 bfr = *(const short8*)&Vtlds[d * KB + (kvb ^ (8 * (d & 7)))];
                #pragma unroll
                for (int q2 = 0; q2 < 4; ++q2)
                    oacc[q2][dt] = __builtin_amdgcn_mfma_f32_16x16x32_bf16(afr[q2], bfr, oacc[q2][dt], 0, 0, 0);
            }
        }
        __syncthreads();   // (D) Vtlds dead

        if (t + 1 < NKV) {
            stage_V(Xtb, Vtlds, t + 1, w, lane);              // fills dead V buffer
            asm volatile("s_waitcnt vmcnt(8)" ::: "memory");  // drains K(t+1)
            __syncthreads();   // (A) K(t+1) published; V(t+1) flies under QK
        }
    }

    // ---- epilogue: divide by l, store fp32
    #pragma unroll
    for (int q2 = 0; q2 < 4; ++q2) {
        #pragma unroll
        for (int r = 0; r < 4; ++r) {
            const int row = q2 * 16 + kgrp * 4 + r;
            const float inv = 1.f / l_s[row];
            float* op = O + ((size_t)b * SEQ + qt * QB + row) * DIM + w * 64 + col;
            #pragma unroll
            for (int dt = 0; dt < 4; ++dt)
                op[dt * 16] = oacc[q2][dt][r] * inv;
        }
    }
}

extern "C" void kernel_launch(void* const* d_in, const int* in_sizes, int n_in,
                              void* d_out, int out_size, void* d_ws, size_t ws_size,
                              hipStream_t stream) {
    const float* X = (const float*)d_in[0];
    float* Out = (float*)d_out;
    unsigned short* Xbf = (unsigned short*)d_ws;                       // 16.8 MB
    unsigned short* Xt  = Xbf + (size_t)BATCH * SEQ * DIM;             // 16.8 MB

    dim3 pgrid(SEQ / 64, DIM / 64, BATCH);   // 32 x 8 x 8
    hipLaunchKernelGGL(prep_kernel, pgrid, dim3(256), 0, stream, X, Xbf, Xt);

    dim3 grid(BATCH * (SEQ / QB));           // 256 blocks = 1 per CU
    dim3 block(NT);
    hipLaunchKernelGGL(attn_fwd, grid, block, 0, stream, Xbf, Xt, Out);
}

// Round 14
// 230.003 us; speedup vs baseline: 1.1529x; 1.1529x over previous
//
#include <hip/hip_runtime.h>
#include <hip/hip_bf16.h>

#define BATCH 8
#define SEQ   2048
#define DIM   512
#define QB    32
#define KB    32
#define NT    512          // 8 waves
#define NKV   (SEQ / KB)   // 64 KV tiles

typedef __attribute__((ext_vector_type(8))) short short8;
typedef __attribute__((ext_vector_type(4))) float f32x4;
typedef __attribute__((ext_vector_type(4))) unsigned short ushort4v;
typedef __attribute__((ext_vector_type(2))) unsigned short ushort2v;

__device__ __forceinline__ unsigned short f2bf(float f) {
    union { float f; unsigned u; } v; v.f = f;
    return (unsigned short)((v.u + 0x7FFFu + ((v.u >> 16) & 1u)) >> 16);
}

// Row swizzle (validated R4-R13); kv in 0..31 here, terms unchanged.
__device__ __forceinline__ int swz(int kv) {
    return (8 * (kv & 7)) ^ (16 * ((kv >> 3) & 3)) ^ (64 * ((kv >> 3) & 1));
}

// ---- pre-pass: X fp32 -> bf16 (validated R7)
__global__ void to_bf16_kernel(const float* __restrict__ X,
                               unsigned short* __restrict__ Y, int n8) {
    const int i = blockIdx.x * blockDim.x + threadIdx.x;
    if (i >= n8) return;
    const float4 a = ((const float4*)X)[i * 2];
    const float4 b = ((const float4*)X)[i * 2 + 1];
    short8 h;
    h[0] = f2bf(a.x); h[1] = f2bf(a.y); h[2] = f2bf(a.z); h[3] = f2bf(a.w);
    h[4] = f2bf(b.x); h[5] = f2bf(b.y); h[6] = f2bf(b.z); h[7] = f2bf(b.w);
    ((short8*)Y)[i] = h;
}

// score = X·X^T (no scaling), softmax, out = P·X — flash-style, bf16 MFMA.
// R14: QB=KB=32 -> LDS ~44KB -> TWO blocks co-resident per CU (the 2600cy/iter
// barrier dead-time of the 1-block/CU rounds gets overlapped by the partner
// block). Each wave = (qi,ki,dhalf): 16x16 S-tile over half of D (qfrag[8] =
// 32 VGPR), partial sums combined via Sbuf[2] planes in the softmax phase.
__global__ __launch_bounds__(NT, 4)
void attn_fwd(const unsigned short* __restrict__ Xbf, float* __restrict__ O) {
    const int b   = blockIdx.x & 7;          // batch -> XCD pinning
    const int qt  = blockIdx.x >> 3;         // 0..63
    const int tid = threadIdx.x;
    const int lane = tid & 63;
    const int w    = tid >> 6;
    const int col  = lane & 15;
    const int kgrp = lane >> 4;
    const int qi = (w >> 1) & 1;             // q-subtile
    const int ki = w & 1;                    // kv-subtile
    const int dh = w >> 2;                   // D half (0: d<256, 1: d>=256)

    __shared__ alignas(16) unsigned short Klds[KB * DIM];       // 32 KB, swizzled
    __shared__ alignas(16) float Sbuf[2][QB][KB + 4];           // 9.2 KB (partial planes)
    __shared__ alignas(16) unsigned short Pfrag[2][64][8];      // 2 KB, A-frag layout
    __shared__ float m_s[QB], l_s[QB], fac_s[QB];

    const unsigned short* Xb = Xbf + (size_t)b * SEQ * DIM;

    // ---- Q preload: 16 q-rows, HALF of D (8 ks slices) -> 32 VGPR
    short8 qfrag[8];
    {
        const int qrow = qt * QB + qi * 16 + col;
        const unsigned short* qp = Xb + (size_t)qrow * DIM;
        #pragma unroll
        for (int ks = 0; ks < 8; ++ks)
            qfrag[ks] = *(const short8*)(qp + (dh * 8 + ks) * 32 + kgrp * 8);
    }

    if (tid < QB) { m_s[tid] = -INFINITY; l_s[tid] = 0.f; }

    f32x4 oacc[2][4];   // O[32 q][w*64 .. +64 d] : [q2][dt]
    #pragma unroll
    for (int i = 0; i < 2; ++i)
        #pragma unroll
        for (int j = 0; j < 4; ++j)
            oacc[i][j] = (f32x4){0.f, 0.f, 0.f, 0.f};

    for (int t = 0; t < NKV; ++t) {
        __syncthreads();   // (a) prev PV done reading Klds
        // ---- stage K/V tile (bf16, swizzled): kv = tid>>4, 4 chunks along d
        {
            const unsigned short* kp = Xb + (size_t)(t * KB) * DIM;
            const int kv = tid >> 4;
            const unsigned short* src = kp + (size_t)kv * DIM + (tid & 15) * 8;
            unsigned short* dst = &Klds[kv * DIM];
            const int sw = swz(kv);
            #pragma unroll
            for (int i = 0; i < 4; ++i) {
                const int d0 = i * 128 + (tid & 15) * 8;
                *(short8*)(dst + (d0 ^ sw)) = *(const short8*)(src + i * 128);
            }
        }
        __syncthreads();   // (b) tile ready

        // ---- QK^T partial: wave computes S[qi*16..+16][ki*16..+16] over its D-half
        {
            const int kvrow = ki * 16 + col;
            const unsigned short* kbase = &Klds[kvrow * DIM];
            const int sw = swz(kvrow);
            f32x4 sacc = (f32x4){0.f,0.f,0.f,0.f};
            #pragma unroll
            for (int ks = 0; ks < 8; ++ks) {
                short8 kfr = *(const short8*)(kbase + (((dh * 8 + ks) * 32 + kgrp * 8) ^ sw));
                sacc = __builtin_amdgcn_mfma_f32_16x16x32_bf16(qfrag[ks], kfr, sacc, 0, 0, 0);
            }
            #pragma unroll
            for (int r = 0; r < 4; ++r)
                Sbuf[dh][qi * 16 + kgrp * 4 + r][ki * 16 + col] = sacc[r];
        }
        __syncthreads();   // (c) both partial planes ready

        // ---- online softmax: 16 threads/row, 2 scores each (sum the 2 planes)
        {
            const int r = tid >> 4;     // 0..31
            const int c = tid & 15;     // 0..15
            float2 v0 = *(const float2*)&Sbuf[0][r][c * 2];
            float2 v1 = *(const float2*)&Sbuf[1][r][c * 2];
            const float s0 = v0.x + v1.x;
            const float s1 = v0.y + v1.y;
            float mloc = fmaxf(s0, s1);
            mloc = fmaxf(mloc, __shfl_xor(mloc, 1));
            mloc = fmaxf(mloc, __shfl_xor(mloc, 2));
            mloc = fmaxf(mloc, __shfl_xor(mloc, 4));
            mloc = fmaxf(mloc, __shfl_xor(mloc, 8));
            const float mold = m_s[r];
            const float mnew = fmaxf(mold, mloc);
            const float fac  = __expf(mold - mnew);   // exp(-inf)=0 on first tile
            const float p0 = __expf(s0 - mnew);
            const float p1 = __expf(s1 - mnew);
            float lsum = p0 + p1;
            lsum += __shfl_xor(lsum, 1);
            lsum += __shfl_xor(lsum, 2);
            lsum += __shfl_xor(lsum, 4);
            lsum += __shfl_xor(lsum, 8);
            ushort2v pp;
            pp[0] = f2bf(p0); pp[1] = f2bf(p1);
            // value (q=r, kv=2c+jj) -> Pfrag[r>>4][(r&15)+16*(c>>2)][2*(c&3)+jj]
            *(ushort2v*)&Pfrag[r >> 4][(r & 15) + 16 * (c >> 2)][2 * (c & 3)] = pp;
            if (c == 0) {
                m_s[r] = mnew;
                fac_s[r] = fac;
                l_s[r] = l_s[r] * fac + lsum;
            }
        }
        __syncthreads();   // (d) Pfrag/fac ready

        // ---- rescale O, then PV: A from Pfrag (lane-contig b128), B via gather
        #pragma unroll
        for (int q2 = 0; q2 < 2; ++q2) {
            #pragma unroll
            for (int r = 0; r < 4; ++r) {
                const float f = fac_s[q2 * 16 + kgrp * 4 + r];
                #pragma unroll
                for (int dt = 0; dt < 4; ++dt) oacc[q2][dt][r] *= f;
            }
        }
        {
            const int kvb = kgrp * 8;
            short8 afr[2];
            #pragma unroll
            for (int q2 = 0; q2 < 2; ++q2)
                afr[q2] = *(const short8*)&Pfrag[q2][lane][0];
            #pragma unroll
            for (int dt = 0; dt < 4; ++dt) {
                const int d = w * 64 + dt * 16 + col;
                short8 bfr;
                #pragma unroll
                for (int j = 0; j < 8; ++j) {
                    const int kv = kvb + j;
                    bfr[j] = (short)Klds[kv * DIM + (d ^ swz(kv))];
                }
                #pragma unroll
                for (int q2 = 0; q2 < 2; ++q2)
                    oacc[q2][dt] = __builtin_amdgcn_mfma_f32_16x16x32_bf16(afr[q2], bfr, oacc[q2][dt], 0, 0, 0);
            }
        }
    }

    // ---- epilogue: divide by l, store fp32
    #pragma unroll
    for (int q2 = 0; q2 < 2; ++q2) {
        #pragma unroll
        for (int r = 0; r < 4; ++r) {
            const int row = q2 * 16 + kgrp * 4 + r;
            const float inv = 1.f / l_s[row];
            float* op = O + ((size_t)b * SEQ + qt * QB + row) * DIM + w * 64 + col;
            #pragma unroll
            for (int dt = 0; dt < 4; ++dt)
                op[dt * 16] = oacc[q2][dt][r] * inv;
        }
    }
}

extern "C" void kernel_launch(void* const* d_in, const int* in_sizes, int n_in,
                              void* d_out, int out_size, void* d_ws, size_t ws_size,
                              hipStream_t stream) {
    const float* X = (const float*)d_in[0];
    float* Out = (float*)d_out;
    unsigned short* Xbf = (unsigned short*)d_ws;   // 16.8 MB bf16 copy

    const int n8 = BATCH * SEQ * DIM / 8;          // 1,048,576
    hipLaunchKernelGGL(to_bf16_kernel, dim3(n8 / 256), dim3(256), 0, stream, X, Xbf, n8);

    dim3 grid(BATCH * (SEQ / QB));                 // 512 blocks -> target 2/CU
    dim3 block(NT);
    hipLaunchKernelGGL(attn_fwd, grid, block, 0, stream, Xbf, Out);
}

// Round 15
// 183.962 us; speedup vs baseline: 1.4414x; 1.2503x over previous
//
#include <hip/hip_runtime.h>
#include <hip/hip_bf16.h>

#define BATCH 8
#define SEQ   2048
#define DIM   512
#define QB    32
#define KB    64
#define NT    512          // 8 waves
#define NKV   (SEQ / KB)   // 32 KV tiles

typedef __attribute__((ext_vector_type(8))) short short8;
typedef __attribute__((ext_vector_type(4))) float f32x4;
typedef __attribute__((ext_vector_type(4))) unsigned short ushort4v;

__device__ __forceinline__ unsigned short f2bf(float f) {
    union { float f; unsigned u; } v; v.f = f;
    return (unsigned short)((v.u + 0x7FFFu + ((v.u >> 16) & 1u)) >> 16);
}

// K-tile row swizzle (validated R4-R12).
__device__ __forceinline__ int swz(int kv) {
    return (8 * (kv & 7)) ^ (16 * ((kv >> 3) & 3)) ^ (64 * ((kv >> 3) & 1));
}

// ---- pre-pass: X fp32 -> Xbf (row-major bf16) + Xt (transposed bf16 [b][d][s])
__global__ __launch_bounds__(256)
void prep_kernel(const float* __restrict__ X,
                 unsigned short* __restrict__ Xbf,
                 unsigned short* __restrict__ Xt) {
    __shared__ unsigned short T[64][72];
    const int b  = blockIdx.z;
    const int s0 = blockIdx.x * 64;
    const int d0 = blockIdx.y * 64;
    const int tid = threadIdx.x;
    const float* Xb = X + ((size_t)b * SEQ + s0) * DIM + d0;
    unsigned short* Yb = Xbf + ((size_t)b * SEQ + s0) * DIM + d0;
    #pragma unroll
    for (int r = 0; r < 4; ++r) {
        const int s = (tid >> 4) + r * 16;
        const int d = (tid & 15) * 4;
        float4 v = *(const float4*)(Xb + (size_t)s * DIM + d);
        ushort4v h;
        h[0] = f2bf(v.x); h[1] = f2bf(v.y); h[2] = f2bf(v.z); h[3] = f2bf(v.w);
        *(ushort4v*)(Yb + (size_t)s * DIM + d) = h;
        *(ushort4v*)&T[s][d] = h;
    }
    __syncthreads();
    {
        const int d = tid >> 2;
        const int sc = (tid & 3) * 16;
        unsigned short buf[16];
        #pragma unroll
        for (int j = 0; j < 16; ++j) buf[j] = T[sc + j][d];
        unsigned short* o = Xt + ((size_t)b * DIM + d0 + d) * SEQ + s0 + sc;
        *(short8*)(o)     = *(short8*)&buf[0];
        *(short8*)(o + 8) = *(short8*)&buf[8];
    }
}

// Async DMA stage of K tile t (linear dest, pre-swizzled src). 8 instr/thread.
__device__ __forceinline__ void stage_K(const unsigned short* __restrict__ Xb,
                                        unsigned short* klds, int t, int w, int lane) {
    const unsigned short* kp = Xb + (size_t)(t * KB) * DIM;
    #pragma unroll
    for (int k = 0; k < 8; ++k) {
        const int kv = k * 8 + w;
        const int dsrc = (lane * 8) ^ swz(kv);
        const unsigned short* g = kp + (size_t)kv * DIM + dsrc;
        unsigned short* l = klds + kv * DIM;
        __builtin_amdgcn_global_load_lds(
            (__attribute__((address_space(1))) void*)(g),
            (__attribute__((address_space(3))) void*)(l), 16, 0, 0);
    }
}

// Async DMA stage of V^T tile t into vtlds[d][kv] (kv ^= 8*(d&7)). 8 instr/thread.
__device__ __forceinline__ void stage_V(const unsigned short* __restrict__ Xtb,
                                        unsigned short* vtlds, int t, int w, int lane) {
    #pragma unroll
    for (int k = 0; k < 8; ++k) {
        const int r = w * 64 + k * 8 + (lane >> 3);
        const int kvsrc = ((lane & 7) * 8) ^ (8 * (r & 7));
        const unsigned short* g = Xtb + (size_t)r * SEQ + t * KB + kvsrc;
        unsigned short* l = vtlds + (w * 64 + k * 8) * KB;
        __builtin_amdgcn_global_load_lds(
            (__attribute__((address_space(1))) void*)(g),
            (__attribute__((address_space(3))) void*)(l), 16, 0, 0);
    }
}

// score = X·X^T (no scaling), softmax, out = P·X — flash-style, bf16 MFMA.
// R15: SWAPPED QK (mfma(K,Q) -> C = S^T, q = lane col). Softmax fully
// in-register; P through a 4KB Pfrag in PV B-frag layout; PV A = Vt b128.
// Staging: R11's DMA + counted-vmcnt schedule (never vmcnt(0) mid-loop).
__global__ __launch_bounds__(NT, 2)
void attn_fwd(const unsigned short* __restrict__ Xbf,
              const unsigned short* __restrict__ Xt,
              float* __restrict__ O) {
    const int b   = blockIdx.x & 7;          // batch -> XCD pinning
    const int qt  = blockIdx.x >> 3;         // 0..63
    const int tid = threadIdx.x;
    const int lane = tid & 63;
    const int w    = tid >> 6;
    const int col  = lane & 15;
    const int kgrp = lane >> 4;
    const int qs = w >> 2;                   // q-strip (16 rows)
    const int kx = w & 3;                    // QK: kv strip; PV: d block (128)

    __shared__ alignas(16) unsigned short Klds[KB * DIM];     // 64 KB, swizzled
    __shared__ alignas(16) unsigned short Vtlds[DIM * KB];    // 64 KB, [d][kv]
    __shared__ alignas(16) unsigned short Pfrag[2][16][64];   // 4 KB, [qs][q][kv^]
    __shared__ alignas(16) float mpart[2][16][4];             // strip-max exchange
    __shared__ alignas(16) float lpart[2][16][4];             // final l exchange

    const unsigned short* Xb  = Xbf + (size_t)b * SEQ * DIM;
    const unsigned short* Xtb = Xt  + (size_t)b * DIM * SEQ;

    // ---- Q preload (B-operand; same bytes as validated A-frag usage)
    short8 qfrag[16];            // 64 VGPR
    {
        const int qrow = qt * QB + qs * 16 + col;
        const unsigned short* qp = Xb + (size_t)qrow * DIM;
        #pragma unroll
        for (int ks = 0; ks < 16; ++ks)
            qfrag[ks] = *(const short8*)(qp + ks * 32 + kgrp * 8);
    }

    float m_reg = -INFINITY;   // running max for q=col (replicated over kgrp)
    float l_reg = 0.f;         // partial sum for (q=col, strip kx)

    f32x4 oacc[8];   // O^T[d = kx*128 + dt*16 + kgrp*4 + r][q = col]
    #pragma unroll
    for (int i = 0; i < 8; ++i) oacc[i] = (f32x4){0.f, 0.f, 0.f, 0.f};

    // ---- prologue: stage tile 0 (both), full drain once
    stage_K(Xb,  Klds,  0, w, lane);
    stage_V(Xtb, Vtlds, 0, w, lane);
    asm volatile("s_waitcnt vmcnt(0)" ::: "memory");
    __syncthreads();

    for (int t = 0; t < NKV; ++t) {
        // ---- QK^T (swapped): sacc[r] = S^T[kv = kx*16+kgrp*4+r][q = col]
        f32x4 sacc = (f32x4){0.f, 0.f, 0.f, 0.f};
        {
            const int kvrow = kx * 16 + col;
            const unsigned short* kbase = &Klds[kvrow * DIM];
            const int sw = swz(kvrow);
            #pragma unroll
            for (int ks = 0; ks < 16; ++ks) {
                short8 kfr = *(const short8*)(kbase + ((ks * 32 + kgrp * 8) ^ sw));
                sacc = __builtin_amdgcn_mfma_f32_16x16x32_bf16(kfr, qfrag[ks], sacc, 0, 0, 0);
            }
        }
        // strip-max: in-lane over r, cross-kgrp via shfl
        {
            float pm = fmaxf(fmaxf(sacc[0], sacc[1]), fmaxf(sacc[2], sacc[3]));
            pm = fmaxf(pm, __shfl_xor(pm, 16));
            pm = fmaxf(pm, __shfl_xor(pm, 32));
            if (lane < 16) mpart[qs][lane][kx] = pm;
        }
        __syncthreads();   // (B) mpart ready + Klds dead
        if (t + 1 < NKV) stage_K(Xb, Klds, t + 1, w, lane);

        // ---- in-register softmax for q=col
        {
            float4 mp = *(const float4*)&mpart[qs][col][0];
            const float mnew = fmaxf(fmaxf(fmaxf(mp.x, mp.y), fmaxf(mp.z, mp.w)), m_reg);
            const float fac  = __expf(m_reg - mnew);   // exp(-inf)=0 on first tile
            m_reg = mnew;
            const float p0 = __expf(sacc[0] - mnew);
            const float p1 = __expf(sacc[1] - mnew);
            const float p2 = __expf(sacc[2] - mnew);
            const float p3 = __expf(sacc[3] - mnew);
            float ps = (p0 + p1) + (p2 + p3);
            ps += __shfl_xor(ps, 16);
            ps += __shfl_xor(ps, 32);
            l_reg = l_reg * fac + ps;
            ushort4v pw;
            pw[0] = f2bf(p0); pw[1] = f2bf(p1); pw[2] = f2bf(p2); pw[3] = f2bf(p3);
            // elementwise map kv -> kv ^ (8*(q&7)); 4-chunk write, 8-chunk read OK
            *(ushort4v*)&Pfrag[qs][col][(kx * 16 + kgrp * 4) ^ (8 * (col & 7))] = pw;
            // rescale O by per-lane fac (O^T cols are this lane's q)
            #pragma unroll
            for (int dt = 0; dt < 8; ++dt) {
                oacc[dt][0] *= fac; oacc[dt][1] *= fac;
                oacc[dt][2] *= fac; oacc[dt][3] *= fac;
            }
        }
        // drain V(t)'s 8 oldest DMAs; K(t+1)'s 8 stay in flight
        if (t + 1 < NKV) { asm volatile("s_waitcnt vmcnt(8)" ::: "memory"); }
        else             { asm volatile("s_waitcnt vmcnt(0)" ::: "memory"); }
        __syncthreads();   // (C) Pfrag ready

        // ---- PV: O^T[d][q] += Vt[d][kv] * P[kv][q]; A=Vt b128, B=Pfrag b128
        #pragma unroll
        for (int s = 0; s < 2; ++s) {
            const short8 pfr = *(const short8*)
                &Pfrag[qs][col][(s * 32 + kgrp * 8) ^ (8 * (col & 7))];
            #pragma unroll
            for (int dt = 0; dt < 8; ++dt) {
                const int d = kx * 128 + dt * 16 + col;
                const short8 vfr = *(const short8*)
                    &Vtlds[d * KB + ((s * 32 + kgrp * 8) ^ (8 * (d & 7)))];
                oacc[dt] = __builtin_amdgcn_mfma_f32_16x16x32_bf16(vfr, pfr, oacc[dt], 0, 0, 0);
            }
        }
        __syncthreads();   // (D) Vtlds + Pfrag dead

        if (t + 1 < NKV) {
            stage_V(Xtb, Vtlds, t + 1, w, lane);              // fills dead V buffer
            asm volatile("s_waitcnt vmcnt(8)" ::: "memory");  // drains K(t+1)
            __syncthreads();   // (A) K(t+1) published; V(t+1) flies under QK
        }
    }

    // ---- epilogue: combine per-strip l across waves, divide, store fp32
    __syncthreads();
    if (lane < 16) lpart[qs][lane][kx] = l_reg;
    __syncthreads();
    {
        float4 lp = *(const float4*)&lpart[qs][col][0];
        const float inv = 1.f / ((lp.x + lp.y) + (lp.z + lp.w));
        float* op = O + ((size_t)b * SEQ + qt * QB + qs * 16 + col) * DIM
                      + kx * 128 + kgrp * 4;
        #pragma unroll
        for (int dt = 0; dt < 8; ++dt) {
            float4 o4;
            o4.x = oacc[dt][0] * inv; o4.y = oacc[dt][1] * inv;
            o4.z = oacc[dt][2] * inv; o4.w = oacc[dt][3] * inv;
            *(float4*)(op + dt * 16) = o4;
        }
    }
}

extern "C" void kernel_launch(void* const* d_in, const int* in_sizes, int n_in,
                              void* d_out, int out_size, void* d_ws, size_t ws_size,
                              hipStream_t stream) {
    const float* X = (const float*)d_in[0];
    float* Out = (float*)d_out;
    unsigned short* Xbf = (unsigned short*)d_ws;                       // 16.8 MB
    unsigned short* Xt  = Xbf + (size_t)BATCH * SEQ * DIM;             // 16.8 MB

    dim3 pgrid(SEQ / 64, DIM / 64, BATCH);   // 32 x 8 x 8
    hipLaunchKernelGGL(prep_kernel, pgrid, dim3(256), 0, stream, X, Xbf, Xt);

    dim3 grid(BATCH * (SEQ / QB));           // 512 blocks
    dim3 block(NT);
    hipLaunchKernelGGL(attn_fwd, grid, block, 0, stream, Xbf, Xt, Out);
}